// Round 8
// baseline (251.381 us; speedup 1.0000x reference)
//
#include <hip/hip_runtime.h>
#include <cfloat>
#include <cmath>

#define DEVINL __device__ __forceinline__

constexpr int N_ = 4, C_ = 21, H_ = 512, W_ = 512;
constexpr int P_ = 171;           // pooled H/W
constexpr int Q_ = 169;           // point grid: P-3+1
constexpr int NC_ = N_ * C_;      // 84
constexpr int HW_ = H_ * W_;      // 262144 = 2^18
constexpr int PP_ = 29241;        // P_*P_ (pack layout, unpadded)
constexpr int PROW_ = 192;        // padded row stride for pr/la
constexpr int PPAD_ = PROW_ * P_; // 32832 per (n,c) image
constexpr int NCOV_ = 189;        // 9 + 9 + 45 + 45 + 81
constexpr float EPS_ = 5e-4f;
constexpr int RC_ = 43;           // rows per k_cov chunk (4 chunks cover 169)
constexpr int G_ = 43;            // col-quads per row
constexpr int HMROW_ = 172;       // hm row stride (16B aligned: 172*4=688=43*16)
constexpr int HMPL_ = 512 * HMROW_; // per-(n,c) hm plane: 88064 floats

constexpr int NB_CE = 1024;                          // 4 n * 256 row-pairs
constexpr int NB_PL = (NC_ * P_ * G_ + 255) / 256;   // 2413 pool blocks

typedef float f4_t __attribute__((ext_vector_type(4)));
typedef __attribute__((address_space(1))) const void gas_void;
typedef __attribute__((address_space(3))) void las_void;

DEVINL constexpr int tstart(int d) { return d * 9 - d * (d - 1) / 2; }

// ---------------------------------------------------------------------------
// DPP wave reduction: pure VALU, no DS-pipe traffic. Total lands in lane 63.
// ---------------------------------------------------------------------------
template <int CTRL>
DEVINL float dpp_add(float v) {
    int x = __builtin_amdgcn_update_dpp(0, __float_as_int(v), CTRL, 0xF, 0xF, false);
    return v + __int_as_float(x);
}

DEVINL float wave_sum63(float v) {
    v = dpp_add<0x111>(v);   // row_shr:1
    v = dpp_add<0x112>(v);   // row_shr:2
    v = dpp_add<0x114>(v);   // row_shr:4
    v = dpp_add<0x118>(v);   // row_shr:8
    v = dpp_add<0x142>(v);   // row_bcast:15
    v = dpp_add<0x143>(v);   // row_bcast:31
    return v;                // total in lane 63
}

// ---------------------------------------------------------------------------
// k_bits: thread per pooled cell (n,i,j) -> packed one-hot + validity bits.
// Block 0 additionally zeroes cov (ordering via same-stream launch order).
// ---------------------------------------------------------------------------
__global__ __launch_bounds__(256) void k_bits(const int* __restrict__ target,
                                              unsigned* __restrict__ pack,
                                              float* __restrict__ cov) {
    int t = threadIdx.x;
    if (blockIdx.x == 0) {
        for (int k = t; k < NC_ * NCOV_ + 2; k += 256) cov[k] = 0.f;
    }
    int tid = blockIdx.x * 256 + t;
    if (tid >= N_ * PP_) return;
    int cell = tid % PP_;
    int n = tid / PP_;
    int j = cell % P_;
    int i = cell / P_;
    int hl = 3 * i - 1; if (hl < 0) hl = 0;
    int wl = 3 * j - 1; if (wl < 0) wl = 0;
    int hmax = 3 * i + 1, wmax = 3 * j + 1;
    const int* tb = target + (size_t)n * HW_;
    unsigned oh = 0, px = 0;
#pragma unroll
    for (int r = 0; r < 3; ++r) {
        int hh = hl + r;
        bool hv = hh <= hmax;
        const int* trow = tb + hh * W_;
#pragma unroll
        for (int dc = 0; dc < 3; ++dc) {
            int ww = wl + dc;
            int tv = trow[ww];
            if (hv && (ww <= wmax) && tv >= 0 && tv < C_) {
                oh |= 1u << tv;
                px |= 1u << (r * 3 + dc);
            }
        }
    }
    pack[tid] = oh | (px << 23);
}

// ---------------------------------------------------------------------------
// k_ce2: CE + horizontal-pooled-max (hm) emission.
// R7 post-mortem: the 21-plane 2^20-stride gather pins at ~2.1 TB/s under
// every parallelism structure -> it's a pattern floor. So cut BYTES: the pool
// stage's 117 MB score re-read is removable because max-pooling decomposes
// exactly. Each CE block owns 2 full image rows x all 21 classes (via the
// same global_load_lds staging); after the ascending-class CE accumulation
// it also emits hm[c][row][j] = masked 3-col max (29.6 MB total). Per phase,
// wave wv loads the whole 4 KB of plane c0+wv (contiguous per wave).
// CE summation order: classes strictly ascending -> bitwise-identical CE.
// ---------------------------------------------------------------------------
__global__ __launch_bounds__(256) void k_ce2(const float* __restrict__ score,
                                             const int* __restrict__ target,
                                             float* __restrict__ hm,
                                             float* __restrict__ cov) {
    __shared__ float lds[4 * 1024];        // 16 KB: 4 planes x 1024 px
    __shared__ unsigned char lval[1024];   // per-pixel target validity
    __shared__ float rn[4], rc[4];
    int b = blockIdx.x;
    int t = threadIdx.x;
    int wv = t >> 6, lane = t & 63;
    int n = b >> 8;
    int brow = (b & 255) * 2;              // first of the block's 2 image rows
    int bhw = brow * W_;
    const float* sp0 = score + (size_t)n * C_ * HW_ + bhw;

    int4 t4 = *(const int4*)(target + (size_t)n * HW_ + bhw + t * 4);
    unsigned vb = (unsigned)(t4.x >= 0 && t4.x < C_)
                | ((unsigned)(t4.y >= 0 && t4.y < C_) << 8)
                | ((unsigned)(t4.z >= 0 && t4.z < C_) << 16)
                | ((unsigned)(t4.w >= 0 && t4.w < C_) << 24);
    *(unsigned*)&lval[t * 4] = vb;         // visible after first barrier

    float4 se = {0.f, 0.f, 0.f, 0.f};
    float4 stgt = {0.f, 0.f, 0.f, 0.f};
    float* hmn = hm + (size_t)n * C_ * HMPL_ + (size_t)brow * HMROW_;

    for (int ph = 0; ph < 6; ++ph) {
        int c0 = ph * 4;
        int np = (c0 + 4 <= C_) ? 4 : (C_ - c0);
        if (wv < np) {
            int c = c0 + wv;               // wave loads ONE whole plane (4 KB)
#pragma unroll
            for (int k = 0; k < 4; ++k) {
                const float* g = sp0 + (size_t)c * HW_ + k * 256 + lane * 4;
                float* l = &lds[wv * 1024 + k * 256];
                __builtin_amdgcn_global_load_lds((gas_void*)g, (las_void*)l,
                                                 16, 0, 0);
            }
        }
        asm volatile("s_waitcnt vmcnt(0)" ::: "memory");
        __syncthreads();

        // CE consume, ascending class order (bitwise = original)
        for (int u = 0; u < np; ++u) {
            int cc = c0 + u;
            f4_t v = *(const f4_t*)&lds[u * 1024 + t * 4];
            se.x += __expf(v.x);
            se.y += __expf(v.y);
            se.z += __expf(v.z);
            se.w += __expf(v.w);
            if (t4.x == cc) stgt.x = v.x;
            if (t4.y == cc) stgt.y = v.y;
            if (t4.z == cc) stgt.z = v.z;
            if (t4.w == cc) stgt.w = v.w;
        }

        // hm: masked horizontal 3-max, np planes x 2 rows x 171 cols
        int nit = np * 342;
        for (int it = t; it < nit; it += 256) {
            int u = it / 342;
            int rem = it - u * 342;
            int r = rem / 171;
            int j = rem - r * 171;
            int wl = 3 * j - 1; if (wl < 0) wl = 0;
            int wmax = 3 * j + 1;
            const float* ls = &lds[u * 1024 + r * 512];
            const unsigned char* lv = &lval[r * 512];
            float m = -FLT_MAX;
#pragma unroll
            for (int dc = 0; dc < 3; ++dc) {
                int ww = wl + dc;
                if (ww <= wmax && lv[ww]) m = fmaxf(m, ls[ww]);
            }
            hmn[(size_t)(c0 + u) * HMPL_ + (size_t)r * HMROW_ + j] = m;
        }
        __syncthreads();   // WAR: next phase overwrites lds
    }

    float nll = 0.f, cnt = 0.f;
    if (t4.x != 255) { nll += __logf(se.x) - stgt.x; cnt += 1.f; }
    if (t4.y != 255) { nll += __logf(se.y) - stgt.y; cnt += 1.f; }
    if (t4.z != 255) { nll += __logf(se.z) - stgt.z; cnt += 1.f; }
    if (t4.w != 255) { nll += __logf(se.w) - stgt.w; cnt += 1.f; }

    nll = wave_sum63(nll);
    cnt = wave_sum63(cnt);
    if (lane == 63) { rn[wv] = nll; rc[wv] = cnt; }
    __syncthreads();
    if (t == 0)
        atomicAdd(&cov[NC_ * NCOV_ + 0], rn[0] + rn[1] + rn[2] + rn[3]);
    if (t == 64)
        atomicAdd(&cov[NC_ * NCOV_ + 1], rc[0] + rc[1] + rc[2] + rc[3]);
}

// ---------------------------------------------------------------------------
// k_pool2: vertical 3-max over hm + sigmoid + clip; la from pack. Replaces
// the pool role's 117 MB score re-read with ~36 MB of hm reads. Max
// decomposition is exact; sigmoid formula identical -> bit-identical pr/la.
// ---------------------------------------------------------------------------
__global__ __launch_bounds__(256) void k_pool2(const float* __restrict__ hm,
                                               const unsigned* __restrict__ pack,
                                               float* __restrict__ pr,
                                               float* __restrict__ la) {
    int tid = blockIdx.x * 256 + threadIdx.x;
    if (tid >= NC_ * P_ * G_) return;
    int g = tid % G_;
    int rest = tid / G_;
    int i = rest % P_;
    int ncidx = rest / P_;
    int n = ncidx / C_;
    int c = ncidx - n * C_;

    int hl = 3 * i - 1; if (hl < 0) hl = 0;
    int nr = (i == 0) ? 2 : 3;             // hv mask: i=0 has 2 valid rows
    const float* hp = hm + (size_t)ncidx * HMPL_ + (size_t)hl * HMROW_ + 4 * g;
    f4_t m = {-FLT_MAX, -FLT_MAX, -FLT_MAX, -FLT_MAX};
    for (int rr = 0; rr < nr; ++rr) {
        f4_t v = *(const f4_t*)(hp + (size_t)rr * HMROW_);
        m.x = fmaxf(m.x, v.x);
        m.y = fmaxf(m.y, v.y);
        m.z = fmaxf(m.z, v.z);
        m.w = fmaxf(m.w, v.w);
    }
    const unsigned* pkp = pack + n * PP_ + i * P_ + 4 * g;
    size_t ob = (size_t)ncidx * PPAD_ + (size_t)i * PROW_ + 4 * g;

    float p0 = fminf(fmaxf(__builtin_amdgcn_rcpf(1.f + __expf(-m.x)), 1e-6f), 1.f);
    float p1 = fminf(fmaxf(__builtin_amdgcn_rcpf(1.f + __expf(-m.y)), 1e-6f), 1.f);
    float p2 = fminf(fmaxf(__builtin_amdgcn_rcpf(1.f + __expf(-m.z)), 1e-6f), 1.f);
    pr[ob + 0] = p0; la[ob + 0] = ((pkp[0] >> c) & 1u) ? 1.f : 0.f;
    pr[ob + 1] = p1; la[ob + 1] = ((pkp[1] >> c) & 1u) ? 1.f : 0.f;
    pr[ob + 2] = p2; la[ob + 2] = ((pkp[2] >> c) & 1u) ? 1.f : 0.f;
    if (4 * g + 3 < P_) {
        float p3 = fminf(fmaxf(__builtin_amdgcn_rcpf(1.f + __expf(-m.w)), 1e-6f), 1.f);
        pr[ob + 3] = p3; la[ob + 3] = ((pkp[3] >> c) & 1u) ? 1.f : 0.f;
    }
}

// ---------------------------------------------------------------------------
// k_cov v6 (UNCHANGED -- left intact so its true duration surfaces in the
// profile next round): grid (84, 4 chunks, 8 parts), <=27 register-resident
// accumulators per part, DPP reductions, LDS 432 B.
// ---------------------------------------------------------------------------
template <int D0, int D1>
DEVINL void cov_tri(const float* __restrict__ X, float* __restrict__ cov,
                    int nc, int r0, int rend, int s2base,
                    int tid, float (*red)[27]) {
    constexpr int NS2 = ((9 - D0) * (10 - D0) - (9 - D1) * (10 - D1)) / 2;
    constexpr int RLO = D0 / 3;
    constexpr int KOFF = tstart(D0);
    float s2[NS2];
#pragma unroll
    for (int k = 0; k < NS2; ++k) s2[k] = 0.f;

    int nitems = (rend - r0) * G_;
    for (int idx = tid; idx < nitems; idx += 256) {
        int lr = idx / G_;
        int q = idx - lr * G_;
        int x0 = q * 4;
        const float* base = X + (size_t)(r0 + lr) * PROW_ + x0;
        float v[3][8];
#pragma unroll
        for (int r = RLO; r < 3; ++r) {
            float4 u0 = *(const float4*)(base + r * PROW_);
            float4 u1 = *(const float4*)(base + r * PROW_ + 4);
            v[r][0] = u0.x; v[r][1] = u0.y; v[r][2] = u0.z; v[r][3] = u0.w;
            v[r][4] = u1.x; v[r][5] = u1.y; v[r][6] = u1.z; v[r][7] = u1.w;
        }
#pragma unroll
        for (int p = 0; p < 4; ++p) {
            if (x0 + p < Q_) {
                int k = 0;
#pragma unroll
                for (int d = D0; d < D1; ++d)
#pragma unroll
                    for (int e = d; e < 9; ++e) {
                        s2[k] += v[d / 3][p + d % 3] * v[e / 3][p + e % 3];
                        ++k;
                    }
            }
        }
    }

    int lane = tid & 63, wv = tid >> 6;
#pragma unroll
    for (int k = 0; k < NS2; ++k) {
        float v2 = wave_sum63(s2[k]);
        if (lane == 63) red[wv][k] = v2;
    }
    __syncthreads();
    if (tid < NS2) {
        float v2 = red[0][tid] + red[1][tid] + red[2][tid] + red[3][tid];
        atomicAdd(&cov[nc * NCOV_ + s2base + KOFF + tid], v2);
    }
}

template <int RA>
DEVINL void cov_ab(const float* __restrict__ A, const float* __restrict__ B,
                   float* __restrict__ cov, int nc, int r0, int rend,
                   int tid, float (*red)[27]) {
    float sab[27];
#pragma unroll
    for (int k = 0; k < 27; ++k) sab[k] = 0.f;

    int nitems = (rend - r0) * G_;
    for (int idx = tid; idx < nitems; idx += 256) {
        int lr = idx / G_;
        int q = idx - lr * G_;
        int x0 = q * 4;
        size_t off = (size_t)(r0 + lr) * PROW_ + x0;
        float a[8];
        {
            float4 u0 = *(const float4*)(A + off + RA * PROW_);
            float4 u1 = *(const float4*)(A + off + RA * PROW_ + 4);
            a[0] = u0.x; a[1] = u0.y; a[2] = u0.z; a[3] = u0.w;
            a[4] = u1.x; a[5] = u1.y; a[6] = u1.z; a[7] = u1.w;
        }
#pragma unroll
        for (int r = 0; r < 3; ++r) {
            float b[8];
            {
                float4 w0 = *(const float4*)(B + off + r * PROW_);
                float4 w1 = *(const float4*)(B + off + r * PROW_ + 4);
                b[0] = w0.x; b[1] = w0.y; b[2] = w0.z; b[3] = w0.w;
                b[4] = w1.x; b[5] = w1.y; b[6] = w1.z; b[7] = w1.w;
            }
#pragma unroll
            for (int p = 0; p < 4; ++p) {
                if (x0 + p < Q_) {
#pragma unroll
                    for (int dm = 0; dm < 3; ++dm)
#pragma unroll
                        for (int e2 = 0; e2 < 3; ++e2)
                            sab[dm * 9 + r * 3 + e2] += a[p + dm] * b[p + e2];
                }
            }
        }
    }

    int lane = tid & 63, wv = tid >> 6;
#pragma unroll
    for (int k = 0; k < 27; ++k) {
        float v2 = wave_sum63(sab[k]);
        if (lane == 63) red[wv][k] = v2;
    }
    __syncthreads();
    if (tid < 27) {
        float v2 = red[0][tid] + red[1][tid] + red[2][tid] + red[3][tid];
        atomicAdd(&cov[nc * NCOV_ + 108 + RA * 27 + tid], v2);
    }
}

DEVINL void cov_s1(const float* __restrict__ LA, const float* __restrict__ PR,
                   float* __restrict__ cov, int nc, int r0, int rend,
                   int tid, float (*red)[27]) {
    float s1a[9], s1b[9];
#pragma unroll
    for (int k = 0; k < 9; ++k) { s1a[k] = 0.f; s1b[k] = 0.f; }

    int nitems = (rend - r0) * G_;
    for (int idx = tid; idx < nitems; idx += 256) {
        int lr = idx / G_;
        int q = idx - lr * G_;
        int x0 = q * 4;
        size_t off = (size_t)(r0 + lr) * PROW_ + x0;
#pragma unroll
        for (int r = 0; r < 3; ++r) {
            float va[8], vb[8];
            {
                float4 u0 = *(const float4*)(LA + off + r * PROW_);
                float4 u1 = *(const float4*)(LA + off + r * PROW_ + 4);
                va[0] = u0.x; va[1] = u0.y; va[2] = u0.z; va[3] = u0.w;
                va[4] = u1.x; va[5] = u1.y; va[6] = u1.z; va[7] = u1.w;
                float4 w0 = *(const float4*)(PR + off + r * PROW_);
                float4 w1 = *(const float4*)(PR + off + r * PROW_ + 4);
                vb[0] = w0.x; vb[1] = w0.y; vb[2] = w0.z; vb[3] = w0.w;
                vb[4] = w1.x; vb[5] = w1.y; vb[6] = w1.z; vb[7] = w1.w;
            }
#pragma unroll
            for (int p = 0; p < 4; ++p) {
                if (x0 + p < Q_) {
#pragma unroll
                    for (int dc = 0; dc < 3; ++dc) {
                        s1a[r * 3 + dc] += va[p + dc];
                        s1b[r * 3 + dc] += vb[p + dc];
                    }
                }
            }
        }
    }

    int lane = tid & 63, wv = tid >> 6;
#pragma unroll
    for (int k = 0; k < 9; ++k) {
        float v2 = wave_sum63(s1a[k]);
        if (lane == 63) red[wv][k] = v2;
    }
#pragma unroll
    for (int k = 0; k < 9; ++k) {
        float v2 = wave_sum63(s1b[k]);
        if (lane == 63) red[wv][9 + k] = v2;
    }
    __syncthreads();
    if (tid < 18) {
        float v2 = red[0][tid] + red[1][tid] + red[2][tid] + red[3][tid];
        atomicAdd(&cov[nc * NCOV_ + tid], v2);   // 0..8 = s1A, 9..17 = s1B
    }
}

__global__ __launch_bounds__(256) void k_cov(const float* __restrict__ la,
                                             const float* __restrict__ pr,
                                             float* __restrict__ cov) {
    __shared__ float red[4][27];
    int nc = blockIdx.x;
    int chunk = blockIdx.y;
    int part = blockIdx.z;
    int r0 = chunk * RC_;
    int rend = r0 + RC_;
    if (rend > Q_) rend = Q_;
    int tid = threadIdx.x;
    const float* LA = la + (size_t)nc * PPAD_;
    const float* PR = pr + (size_t)nc * PPAD_;

    switch (part) {
        case 0: cov_tri<0, 3>(LA, cov, nc, r0, rend, 18, tid, red); break;
        case 1: cov_tri<3, 9>(LA, cov, nc, r0, rend, 18, tid, red); break;
        case 2: cov_tri<0, 3>(PR, cov, nc, r0, rend, 63, tid, red); break;
        case 3: cov_tri<3, 9>(PR, cov, nc, r0, rend, 63, tid, red); break;
        case 4: cov_ab<0>(LA, PR, cov, nc, r0, rend, tid, red); break;
        case 5: cov_ab<1>(LA, PR, cov, nc, r0, rend, tid, red); break;
        case 6: cov_ab<2>(LA, PR, cov, nc, r0, rend, tid, red); break;
        case 7: cov_s1(LA, PR, cov, nc, r0, rend, tid, red); break;
    }
}

// ---------------------------------------------------------------------------
// k_final: per-(n,c) 9x9 algebra. UNCHANGED.
// ---------------------------------------------------------------------------
__global__ __launch_bounds__(128) void k_final(const float* __restrict__ cov,
                                               float* __restrict__ out) {
    __shared__ float red[128];
    int t = threadIdx.x;
    float my = 0.f;
    if (t < NC_) {
        const float* S = cov + t * NCOV_;
        const float Lf = (float)(Q_ * Q_);  // 28561
        float sA[9], sB[9];
#pragma unroll
        for (int d = 0; d < 9; ++d) { sA[d] = S[d]; sB[d] = S[9 + d]; }
        float laC[45], M[45], Cm[81];
        {
            int k = 0;
#pragma unroll
            for (int d = 0; d < 9; ++d)
#pragma unroll
                for (int e = d; e < 9; ++e) {
                    laC[k] = S[18 + k] - sA[d] * sA[e] / Lf;
                    M[k] = S[63 + k] - sB[d] * sB[e] / Lf + (d == e ? EPS_ : 0.f);
                    ++k;
                }
#pragma unroll
            for (int d = 0; d < 9; ++d)
#pragma unroll
                for (int e = 0; e < 9; ++e)
                    Cm[d * 9 + e] = S[108 + d * 9 + e] - sA[d] * sB[e] / Lf;
        }
#pragma unroll
        for (int j = 0; j < 9; ++j) {
            float s = M[tstart(j)];
#pragma unroll
            for (int k = 0; k < j; ++k) { float l = M[tstart(k) + (j - k)]; s -= l * l; }
            float dj = sqrtf(fmaxf(s, 1e-30f));
            M[tstart(j)] = dj;
            float inv = 1.f / dj;
#pragma unroll
            for (int i = j + 1; i < 9; ++i) {
                float s2 = M[tstart(j) + (i - j)];
#pragma unroll
                for (int k = 0; k < j; ++k)
                    s2 -= M[tstart(k) + (i - k)] * M[tstart(k) + (j - k)];
                M[tstart(j) + (i - j)] = s2 * inv;
            }
        }
#pragma unroll
        for (int p = 0; p < 9; ++p) {
#pragma unroll
            for (int i = 0; i < 9; ++i) {
                float s = Cm[p * 9 + i];
#pragma unroll
                for (int k = 0; k < i; ++k)
                    s -= M[tstart(k) + (i - k)] * Cm[p * 9 + k];
                Cm[p * 9 + i] = s / M[tstart(i)];
            }
        }
#pragma unroll
        for (int d = 0; d < 9; ++d)
#pragma unroll
            for (int e = d; e < 9; ++e) {
                float s = 0.f;
#pragma unroll
                for (int i = 0; i < 9; ++i) s += Cm[d * 9 + i] * Cm[e * 9 + i];
                laC[tstart(d) + (e - d)] -= s;
                if (d == e) laC[tstart(d)] += EPS_;
            }
        float rmi = 0.f;
#pragma unroll
        for (int j = 0; j < 9; ++j) {
            float s = laC[tstart(j)];
#pragma unroll
            for (int k = 0; k < j; ++k) { float l = laC[tstart(k) + (j - k)]; s -= l * l; }
            float dj = sqrtf(fmaxf(s, 0.f));
            laC[tstart(j)] = dj;
            float inv = 1.f / fmaxf(dj, 1e-30f);
#pragma unroll
            for (int i = j + 1; i < 9; ++i) {
                float s2 = laC[tstart(j) + (i - j)];
#pragma unroll
                for (int k = 0; k < j; ++k)
                    s2 -= laC[tstart(k) + (i - k)] * laC[tstart(k) + (j - k)];
                laC[tstart(j) + (i - j)] = s2 * inv;
            }
            rmi += __logf(dj + 1e-8f);
        }
        my = rmi;
    }
    red[t] = my;
    __syncthreads();
#pragma unroll
    for (int o = 64; o > 0; o >>= 1) {
        if (t < o) red[t] += red[t + o];
        __syncthreads();
    }
    if (t == 0) {
        float rmi_total = red[0] / 36.f;  // / (N * HALF_D)
        float ce = cov[NC_ * NCOV_ + 0] / cov[NC_ * NCOV_ + 1];
        out[0] = 0.5f * ce + 0.5f * rmi_total;
    }
}

extern "C" void kernel_launch(void* const* d_in, const int* in_sizes, int n_in,
                              void* d_out, int out_size, void* d_ws, size_t ws_size,
                              hipStream_t stream) {
    const float* score = (const float*)d_in[0];
    const int* target = (const int*)d_in[1];
    float* pr = (float*)d_ws;
    float* la = pr + (size_t)NC_ * PPAD_;
    float* hm = la + (size_t)NC_ * PPAD_;               // 29.6 MB, 16B-aligned
    float* cov = hm + (size_t)NC_ * HMPL_;              // NC_*NCOV_ + 2 floats
    unsigned* pack = (unsigned*)(cov + NC_ * NCOV_ + 2);

    k_bits<<<dim3((N_ * PP_ + 255) / 256), dim3(256), 0, stream>>>(target, pack, cov);
    k_ce2<<<dim3(NB_CE), dim3(256), 0, stream>>>(score, target, hm, cov);
    k_pool2<<<dim3(NB_PL), dim3(256), 0, stream>>>(hm, pack, pr, la);
    k_cov<<<dim3(NC_, 4, 8), dim3(256), 0, stream>>>(la, pr, cov);
    k_final<<<dim3(1), dim3(128), 0, stream>>>(cov, (float*)d_out);
}

// Round 9
// 234.592 us; speedup vs baseline: 1.0716x; 1.0716x over previous
//
#include <hip/hip_runtime.h>
#include <cfloat>
#include <cmath>

#define DEVINL __device__ __forceinline__

constexpr int N_ = 4, C_ = 21, H_ = 512, W_ = 512;
constexpr int P_ = 171;           // pooled H/W
constexpr int Q_ = 169;           // point grid: P-3+1
constexpr int NC_ = N_ * C_;      // 84
constexpr int HW_ = H_ * W_;      // 262144 = 2^18
constexpr int PP_ = 29241;        // P_*P_ (pack layout, unpadded)
constexpr int PROW_ = 192;        // padded row stride for pr/la
constexpr int PPAD_ = PROW_ * P_; // 32832 per (n,c) image
constexpr int NCOV_ = 189;        // 9 + 9 + 45 + 45 + 81
constexpr float EPS_ = 5e-4f;
constexpr int G_ = 43;            // col-quads per row
constexpr int HMROW_ = 172;       // hm row stride (16B aligned)
constexpr int HMPL_ = 512 * HMROW_; // per-(n,c) hm plane

constexpr int NB_CE = 1024;                          // 4 n * 256 row-pairs
constexpr int NB_PL = (NC_ * P_ * G_ + 255) / 256;   // 2413 pool blocks

typedef float f4_t __attribute__((ext_vector_type(4)));
typedef __attribute__((address_space(1))) const void gas_void;
typedef __attribute__((address_space(3))) void las_void;

DEVINL constexpr int tstart(int d) { return d * 9 - d * (d - 1) / 2; }

// ---------------------------------------------------------------------------
// DPP wave reduction: pure VALU, no DS-pipe traffic. Total lands in lane 63.
// ---------------------------------------------------------------------------
template <int CTRL>
DEVINL float dpp_add(float v) {
    int x = __builtin_amdgcn_update_dpp(0, __float_as_int(v), CTRL, 0xF, 0xF, false);
    return v + __int_as_float(x);
}

DEVINL float wave_sum63(float v) {
    v = dpp_add<0x111>(v);   // row_shr:1
    v = dpp_add<0x112>(v);   // row_shr:2
    v = dpp_add<0x114>(v);   // row_shr:4
    v = dpp_add<0x118>(v);   // row_shr:8
    v = dpp_add<0x142>(v);   // row_bcast:15
    v = dpp_add<0x143>(v);   // row_bcast:31
    return v;                // total in lane 63
}

// ---------------------------------------------------------------------------
// k_bits: thread per pooled cell (n,i,j) -> packed one-hot + validity bits.
// Block 0 additionally zeroes cov.
// ---------------------------------------------------------------------------
__global__ __launch_bounds__(256) void k_bits(const int* __restrict__ target,
                                              unsigned* __restrict__ pack,
                                              float* __restrict__ cov) {
    int t = threadIdx.x;
    if (blockIdx.x == 0) {
        for (int k = t; k < NC_ * NCOV_ + 2; k += 256) cov[k] = 0.f;
    }
    int tid = blockIdx.x * 256 + t;
    if (tid >= N_ * PP_) return;
    int cell = tid % PP_;
    int n = tid / PP_;
    int j = cell % P_;
    int i = cell / P_;
    int hl = 3 * i - 1; if (hl < 0) hl = 0;
    int wl = 3 * j - 1; if (wl < 0) wl = 0;
    int hmax = 3 * i + 1, wmax = 3 * j + 1;
    const int* tb = target + (size_t)n * HW_;
    unsigned oh = 0, px = 0;
#pragma unroll
    for (int r = 0; r < 3; ++r) {
        int hh = hl + r;
        bool hv = hh <= hmax;
        const int* trow = tb + hh * W_;
#pragma unroll
        for (int dc = 0; dc < 3; ++dc) {
            int ww = wl + dc;
            int tv = trow[ww];
            if (hv && (ww <= wmax) && tv >= 0 && tv < C_) {
                oh |= 1u << tv;
                px |= 1u << (r * 3 + dc);
            }
        }
    }
    pack[tid] = oh | (px << 23);
}

// ---------------------------------------------------------------------------
// k_ce2: CE + horizontal-pooled-max (hm) emission. UNCHANGED (R8-verified).
// ---------------------------------------------------------------------------
__global__ __launch_bounds__(256) void k_ce2(const float* __restrict__ score,
                                             const int* __restrict__ target,
                                             float* __restrict__ hm,
                                             float* __restrict__ cov) {
    __shared__ float lds[4 * 1024];        // 16 KB: 4 planes x 1024 px
    __shared__ unsigned char lval[1024];   // per-pixel target validity
    __shared__ float rn[4], rc[4];
    int b = blockIdx.x;
    int t = threadIdx.x;
    int wv = t >> 6, lane = t & 63;
    int n = b >> 8;
    int brow = (b & 255) * 2;              // first of the block's 2 image rows
    int bhw = brow * W_;
    const float* sp0 = score + (size_t)n * C_ * HW_ + bhw;

    int4 t4 = *(const int4*)(target + (size_t)n * HW_ + bhw + t * 4);
    unsigned vb = (unsigned)(t4.x >= 0 && t4.x < C_)
                | ((unsigned)(t4.y >= 0 && t4.y < C_) << 8)
                | ((unsigned)(t4.z >= 0 && t4.z < C_) << 16)
                | ((unsigned)(t4.w >= 0 && t4.w < C_) << 24);
    *(unsigned*)&lval[t * 4] = vb;         // visible after first barrier

    float4 se = {0.f, 0.f, 0.f, 0.f};
    float4 stgt = {0.f, 0.f, 0.f, 0.f};
    float* hmn = hm + (size_t)n * C_ * HMPL_ + (size_t)brow * HMROW_;

    for (int ph = 0; ph < 6; ++ph) {
        int c0 = ph * 4;
        int np = (c0 + 4 <= C_) ? 4 : (C_ - c0);
        if (wv < np) {
            int c = c0 + wv;               // wave loads ONE whole plane (4 KB)
#pragma unroll
            for (int k = 0; k < 4; ++k) {
                const float* g = sp0 + (size_t)c * HW_ + k * 256 + lane * 4;
                float* l = &lds[wv * 1024 + k * 256];
                __builtin_amdgcn_global_load_lds((gas_void*)g, (las_void*)l,
                                                 16, 0, 0);
            }
        }
        asm volatile("s_waitcnt vmcnt(0)" ::: "memory");
        __syncthreads();

        // CE consume, ascending class order (bitwise = original)
        for (int u = 0; u < np; ++u) {
            int cc = c0 + u;
            f4_t v = *(const f4_t*)&lds[u * 1024 + t * 4];
            se.x += __expf(v.x);
            se.y += __expf(v.y);
            se.z += __expf(v.z);
            se.w += __expf(v.w);
            if (t4.x == cc) stgt.x = v.x;
            if (t4.y == cc) stgt.y = v.y;
            if (t4.z == cc) stgt.z = v.z;
            if (t4.w == cc) stgt.w = v.w;
        }

        // hm: masked horizontal 3-max, np planes x 2 rows x 171 cols
        int nit = np * 342;
        for (int it = t; it < nit; it += 256) {
            int u = it / 342;
            int rem = it - u * 342;
            int r = rem / 171;
            int j = rem - r * 171;
            int wl = 3 * j - 1; if (wl < 0) wl = 0;
            int wmax = 3 * j + 1;
            const float* ls = &lds[u * 1024 + r * 512];
            const unsigned char* lv = &lval[r * 512];
            float m = -FLT_MAX;
#pragma unroll
            for (int dc = 0; dc < 3; ++dc) {
                int ww = wl + dc;
                if (ww <= wmax && lv[ww]) m = fmaxf(m, ls[ww]);
            }
            hmn[(size_t)(c0 + u) * HMPL_ + (size_t)r * HMROW_ + j] = m;
        }
        __syncthreads();   // WAR: next phase overwrites lds
    }

    float nll = 0.f, cnt = 0.f;
    if (t4.x != 255) { nll += __logf(se.x) - stgt.x; cnt += 1.f; }
    if (t4.y != 255) { nll += __logf(se.y) - stgt.y; cnt += 1.f; }
    if (t4.z != 255) { nll += __logf(se.z) - stgt.z; cnt += 1.f; }
    if (t4.w != 255) { nll += __logf(se.w) - stgt.w; cnt += 1.f; }

    nll = wave_sum63(nll);
    cnt = wave_sum63(cnt);
    if (lane == 63) { rn[wv] = nll; rc[wv] = cnt; }
    __syncthreads();
    if (t == 0)
        atomicAdd(&cov[NC_ * NCOV_ + 0], rn[0] + rn[1] + rn[2] + rn[3]);
    if (t == 64)
        atomicAdd(&cov[NC_ * NCOV_ + 1], rc[0] + rc[1] + rc[2] + rc[3]);
}

// ---------------------------------------------------------------------------
// k_pool2: vertical 3-max over hm + sigmoid + clip. UNCHANGED (R8-verified).
// ---------------------------------------------------------------------------
__global__ __launch_bounds__(256) void k_pool2(const float* __restrict__ hm,
                                               const unsigned* __restrict__ pack,
                                               float* __restrict__ pr,
                                               float* __restrict__ la) {
    int tid = blockIdx.x * 256 + threadIdx.x;
    if (tid >= NC_ * P_ * G_) return;
    int g = tid % G_;
    int rest = tid / G_;
    int i = rest % P_;
    int ncidx = rest / P_;
    int n = ncidx / C_;
    int c = ncidx - n * C_;

    int hl = 3 * i - 1; if (hl < 0) hl = 0;
    int nr = (i == 0) ? 2 : 3;
    const float* hp = hm + (size_t)ncidx * HMPL_ + (size_t)hl * HMROW_ + 4 * g;
    f4_t m = {-FLT_MAX, -FLT_MAX, -FLT_MAX, -FLT_MAX};
    for (int rr = 0; rr < nr; ++rr) {
        f4_t v = *(const f4_t*)(hp + (size_t)rr * HMROW_);
        m.x = fmaxf(m.x, v.x);
        m.y = fmaxf(m.y, v.y);
        m.z = fmaxf(m.z, v.z);
        m.w = fmaxf(m.w, v.w);
    }
    const unsigned* pkp = pack + n * PP_ + i * P_ + 4 * g;
    size_t ob = (size_t)ncidx * PPAD_ + (size_t)i * PROW_ + 4 * g;

    float p0 = fminf(fmaxf(__builtin_amdgcn_rcpf(1.f + __expf(-m.x)), 1e-6f), 1.f);
    float p1 = fminf(fmaxf(__builtin_amdgcn_rcpf(1.f + __expf(-m.y)), 1e-6f), 1.f);
    float p2 = fminf(fmaxf(__builtin_amdgcn_rcpf(1.f + __expf(-m.z)), 1e-6f), 1.f);
    pr[ob + 0] = p0; la[ob + 0] = ((pkp[0] >> c) & 1u) ? 1.f : 0.f;
    pr[ob + 1] = p1; la[ob + 1] = ((pkp[1] >> c) & 1u) ? 1.f : 0.f;
    pr[ob + 2] = p2; la[ob + 2] = ((pkp[2] >> c) & 1u) ? 1.f : 0.f;
    if (4 * g + 3 < P_) {
        float p3 = fminf(fmaxf(__builtin_amdgcn_rcpf(1.f + __expf(-m.w)), 1e-6f), 1.f);
        pr[ob + 3] = p3; la[ob + 3] = ((pkp[3] >> c) & 1u) ? 1.f : 0.f;
    }
}

// ---------------------------------------------------------------------------
// k_cov v7. R8 counters: 58us, VALU 30%, occ 45%, HBM 3% -> latency-bound
// with structural overhead. FMA floor is 5.8us. v7 raises FMA-per-load ~6x:
//  - 3 merged parts (A: la tri+s1A 54acc, B: pr tri+s1B 54acc, C: cross 81acc)
//  - thread owns (col-quad, ~11-row strip); 3-row REGISTER window slides down
//    the strip with 1-row-ahead prefetch (4-buffer static rotation -- no
//    runtime indexing, rule #20). Each row loaded once (was 3x per part).
//  - part C: 324 FMA per 4 loads; reductions 2.7x fewer (1008 vs 2688 blocks)
// grid (84, 4, 3) x 192 threads = 3024 waves (all-resident).
// __launch_bounds__(192,2) caps VGPR<=256: the 81-acc part cannot spill
// (R3 scratch lesson) while actual ~160 VGPR -> 3 waves/SIMD, ILP hides L2.
// ---------------------------------------------------------------------------
DEVINL void ldrow(float (&dst)[8], const float* Xb, int row) {
    const float* p = Xb + (size_t)row * PROW_;
    f4_t u0 = *(const f4_t*)p;
    f4_t u1 = *(const f4_t*)(p + 4);
    dst[0] = u0.x; dst[1] = u0.y; dst[2] = u0.z; dst[3] = u0.w;
    dst[4] = u1.x; dst[5] = u1.y; dst[6] = u1.z; dst[7] = u1.w;
}

DEVINL void tri_step(float (&acc)[54], const float (&A)[8], const float (&B)[8],
                     const float (&C)[8], int x0) {
#pragma unroll
    for (int p = 0; p < 4; ++p) {
        if (x0 + p < Q_) {
            float v[9] = {A[p], A[p + 1], A[p + 2], B[p], B[p + 1], B[p + 2],
                          C[p], C[p + 1], C[p + 2]};
#pragma unroll
            for (int d = 0; d < 9; ++d) acc[d] += v[d];
            int k = 9;
#pragma unroll
            for (int d = 0; d < 9; ++d)
#pragma unroll
                for (int e = d; e < 9; ++e) { acc[k] += v[d] * v[e]; ++k; }
        }
    }
}

DEVINL void ab_step(float (&acc)[81], const float (&A0)[8], const float (&A1)[8],
                    const float (&A2)[8], const float (&B0)[8], const float (&B1)[8],
                    const float (&B2)[8], int x0) {
#pragma unroll
    for (int p = 0; p < 4; ++p) {
        if (x0 + p < Q_) {
            float v[9] = {A0[p], A0[p + 1], A0[p + 2], A1[p], A1[p + 1], A1[p + 2],
                          A2[p], A2[p + 1], A2[p + 2]};
            float w[9] = {B0[p], B0[p + 1], B0[p + 2], B1[p], B1[p + 1], B1[p + 2],
                          B2[p], B2[p + 1], B2[p + 2]};
#pragma unroll
            for (int d = 0; d < 9; ++d)
#pragma unroll
                for (int e = 0; e < 9; ++e) acc[d * 9 + e] += v[d] * w[e];
        }
    }
}

DEVINL void cov_tri_strip(const float* __restrict__ X, float* __restrict__ cov,
                          int nc, int r0, int rend, int s1base, int s2base,
                          int tid, float (*red)[81]) {
    float acc[54];
#pragma unroll
    for (int k = 0; k < 54; ++k) acc[k] = 0.f;

    if (tid < 4 * G_) {
        int s = tid / G_, q = tid - s * G_;
        int len = rend - r0, sl = (len + 3) >> 2;
        int a0 = r0 + s * sl;
        int a1 = a0 + sl; if (a1 > rend) a1 = rend;
        if (a0 < a1) {
            int x0 = 4 * q;
            const float* Xb = X + x0;
            float R0[8], R1[8], R2[8], R3[8];
            ldrow(R0, Xb, a0); ldrow(R1, Xb, a0 + 1); ldrow(R2, Xb, a0 + 2);
            int i = a0;
            while (i + 4 <= a1) {
                ldrow(R3, Xb, i + 3);                       tri_step(acc, R0, R1, R2, x0);
                ldrow(R0, Xb, i + 4);                       tri_step(acc, R1, R2, R3, x0);
                ldrow(R1, Xb, i + 5);                       tri_step(acc, R2, R3, R0, x0);
                ldrow(R2, Xb, (i + 6 < P_) ? i + 6 : P_ - 1); tri_step(acc, R3, R0, R1, x0);
                i += 4;
            }
            int rem = a1 - i;
            if (rem >= 1) tri_step(acc, R0, R1, R2, x0);
            if (rem >= 2) { ldrow(R3, Xb, i + 3); tri_step(acc, R1, R2, R3, x0); }
            if (rem >= 3) { ldrow(R0, Xb, (i + 4 < P_) ? i + 4 : P_ - 1);
                            tri_step(acc, R2, R3, R0, x0); }
        }
    }

    int lane = tid & 63, wv = tid >> 6;
#pragma unroll
    for (int k = 0; k < 54; ++k) {
        float v2 = wave_sum63(acc[k]);
        if (lane == 63) red[wv][k] = v2;
    }
    __syncthreads();
    if (tid < 54) {
        float v2 = red[0][tid] + red[1][tid] + red[2][tid];
        int dst = (tid < 9) ? (s1base + tid) : (s2base + tid - 9);
        atomicAdd(&cov[nc * NCOV_ + dst], v2);
    }
}

DEVINL void cov_ab_strip(const float* __restrict__ LA, const float* __restrict__ PR,
                         float* __restrict__ cov, int nc, int r0, int rend,
                         int tid, float (*red)[81]) {
    float acc[81];
#pragma unroll
    for (int k = 0; k < 81; ++k) acc[k] = 0.f;

    if (tid < 4 * G_) {
        int s = tid / G_, q = tid - s * G_;
        int len = rend - r0, sl = (len + 3) >> 2;
        int a0 = r0 + s * sl;
        int a1 = a0 + sl; if (a1 > rend) a1 = rend;
        if (a0 < a1) {
            int x0 = 4 * q;
            const float* Lb = LA + x0;
            const float* Pb = PR + x0;
            float L0[8], L1[8], L2[8], L3[8];
            float Pv0[8], Pv1[8], Pv2[8], Pv3[8];
            ldrow(L0, Lb, a0);     ldrow(Pv0, Pb, a0);
            ldrow(L1, Lb, a0 + 1); ldrow(Pv1, Pb, a0 + 1);
            ldrow(L2, Lb, a0 + 2); ldrow(Pv2, Pb, a0 + 2);
            int i = a0;
            while (i + 4 <= a1) {
                ldrow(L3, Lb, i + 3); ldrow(Pv3, Pb, i + 3);
                ab_step(acc, L0, L1, L2, Pv0, Pv1, Pv2, x0);
                ldrow(L0, Lb, i + 4); ldrow(Pv0, Pb, i + 4);
                ab_step(acc, L1, L2, L3, Pv1, Pv2, Pv3, x0);
                ldrow(L1, Lb, i + 5); ldrow(Pv1, Pb, i + 5);
                ab_step(acc, L2, L3, L0, Pv2, Pv3, Pv0, x0);
                int pre = (i + 6 < P_) ? i + 6 : P_ - 1;
                ldrow(L2, Lb, pre); ldrow(Pv2, Pb, pre);
                ab_step(acc, L3, L0, L1, Pv3, Pv0, Pv1, x0);
                i += 4;
            }
            int rem = a1 - i;
            if (rem >= 1) ab_step(acc, L0, L1, L2, Pv0, Pv1, Pv2, x0);
            if (rem >= 2) { ldrow(L3, Lb, i + 3); ldrow(Pv3, Pb, i + 3);
                            ab_step(acc, L1, L2, L3, Pv1, Pv2, Pv3, x0); }
            if (rem >= 3) { int pre = (i + 4 < P_) ? i + 4 : P_ - 1;
                            ldrow(L0, Lb, pre); ldrow(Pv0, Pb, pre);
                            ab_step(acc, L2, L3, L0, Pv2, Pv3, Pv0, x0); }
        }
    }

    int lane = tid & 63, wv = tid >> 6;
#pragma unroll
    for (int k = 0; k < 81; ++k) {
        float v2 = wave_sum63(acc[k]);
        if (lane == 63) red[wv][k] = v2;
    }
    __syncthreads();
    if (tid < 81) {
        float v2 = red[0][tid] + red[1][tid] + red[2][tid];
        atomicAdd(&cov[nc * NCOV_ + 108 + tid], v2);
    }
}

__global__ __launch_bounds__(192, 2) void k_cov(const float* __restrict__ la,
                                                const float* __restrict__ pr,
                                                float* __restrict__ cov) {
    __shared__ float red[3][81];
    int nc = blockIdx.x;
    int chunk = blockIdx.y;
    int part = blockIdx.z;
    int r0 = chunk * 43;
    int rend = r0 + 43;
    if (rend > Q_) rend = Q_;
    int tid = threadIdx.x;
    const float* LA = la + (size_t)nc * PPAD_;
    const float* PR = pr + (size_t)nc * PPAD_;

    switch (part) {
        case 0: cov_tri_strip(LA, cov, nc, r0, rend, 0, 18, tid, red); break;
        case 1: cov_tri_strip(PR, cov, nc, r0, rend, 9, 63, tid, red); break;
        case 2: cov_ab_strip(LA, PR, cov, nc, r0, rend, tid, red); break;
    }
}

// ---------------------------------------------------------------------------
// k_final: per-(n,c) 9x9 algebra. UNCHANGED.
// ---------------------------------------------------------------------------
__global__ __launch_bounds__(128) void k_final(const float* __restrict__ cov,
                                               float* __restrict__ out) {
    __shared__ float red[128];
    int t = threadIdx.x;
    float my = 0.f;
    if (t < NC_) {
        const float* S = cov + t * NCOV_;
        const float Lf = (float)(Q_ * Q_);  // 28561
        float sA[9], sB[9];
#pragma unroll
        for (int d = 0; d < 9; ++d) { sA[d] = S[d]; sB[d] = S[9 + d]; }
        float laC[45], M[45], Cm[81];
        {
            int k = 0;
#pragma unroll
            for (int d = 0; d < 9; ++d)
#pragma unroll
                for (int e = d; e < 9; ++e) {
                    laC[k] = S[18 + k] - sA[d] * sA[e] / Lf;
                    M[k] = S[63 + k] - sB[d] * sB[e] / Lf + (d == e ? EPS_ : 0.f);
                    ++k;
                }
#pragma unroll
            for (int d = 0; d < 9; ++d)
#pragma unroll
                for (int e = 0; e < 9; ++e)
                    Cm[d * 9 + e] = S[108 + d * 9 + e] - sA[d] * sB[e] / Lf;
        }
#pragma unroll
        for (int j = 0; j < 9; ++j) {
            float s = M[tstart(j)];
#pragma unroll
            for (int k = 0; k < j; ++k) { float l = M[tstart(k) + (j - k)]; s -= l * l; }
            float dj = sqrtf(fmaxf(s, 1e-30f));
            M[tstart(j)] = dj;
            float inv = 1.f / dj;
#pragma unroll
            for (int i = j + 1; i < 9; ++i) {
                float s2 = M[tstart(j) + (i - j)];
#pragma unroll
                for (int k = 0; k < j; ++k)
                    s2 -= M[tstart(k) + (i - k)] * M[tstart(k) + (j - k)];
                M[tstart(j) + (i - j)] = s2 * inv;
            }
        }
#pragma unroll
        for (int p = 0; p < 9; ++p) {
#pragma unroll
            for (int i = 0; i < 9; ++i) {
                float s = Cm[p * 9 + i];
#pragma unroll
                for (int k = 0; k < i; ++k)
                    s -= M[tstart(k) + (i - k)] * Cm[p * 9 + k];
                Cm[p * 9 + i] = s / M[tstart(i)];
            }
        }
#pragma unroll
        for (int d = 0; d < 9; ++d)
#pragma unroll
            for (int e = d; e < 9; ++e) {
                float s = 0.f;
#pragma unroll
                for (int i = 0; i < 9; ++i) s += Cm[d * 9 + i] * Cm[e * 9 + i];
                laC[tstart(d) + (e - d)] -= s;
                if (d == e) laC[tstart(d)] += EPS_;
            }
        float rmi = 0.f;
#pragma unroll
        for (int j = 0; j < 9; ++j) {
            float s = laC[tstart(j)];
#pragma unroll
            for (int k = 0; k < j; ++k) { float l = laC[tstart(k) + (j - k)]; s -= l * l; }
            float dj = sqrtf(fmaxf(s, 0.f));
            laC[tstart(j)] = dj;
            float inv = 1.f / fmaxf(dj, 1e-30f);
#pragma unroll
            for (int i = j + 1; i < 9; ++i) {
                float s2 = laC[tstart(j) + (i - j)];
#pragma unroll
                for (int k = 0; k < j; ++k)
                    s2 -= laC[tstart(k) + (i - k)] * laC[tstart(k) + (j - k)];
                laC[tstart(j) + (i - j)] = s2 * inv;
            }
            rmi += __logf(dj + 1e-8f);
        }
        my = rmi;
    }
    red[t] = my;
    __syncthreads();
#pragma unroll
    for (int o = 64; o > 0; o >>= 1) {
        if (t < o) red[t] += red[t + o];
        __syncthreads();
    }
    if (t == 0) {
        float rmi_total = red[0] / 36.f;  // / (N * HALF_D)
        float ce = cov[NC_ * NCOV_ + 0] / cov[NC_ * NCOV_ + 1];
        out[0] = 0.5f * ce + 0.5f * rmi_total;
    }
}

extern "C" void kernel_launch(void* const* d_in, const int* in_sizes, int n_in,
                              void* d_out, int out_size, void* d_ws, size_t ws_size,
                              hipStream_t stream) {
    const float* score = (const float*)d_in[0];
    const int* target = (const int*)d_in[1];
    float* pr = (float*)d_ws;
    float* la = pr + (size_t)NC_ * PPAD_;
    float* hm = la + (size_t)NC_ * PPAD_;               // 29.6 MB, 16B-aligned
    float* cov = hm + (size_t)NC_ * HMPL_;              // NC_*NCOV_ + 2 floats
    unsigned* pack = (unsigned*)(cov + NC_ * NCOV_ + 2);

    k_bits<<<dim3((N_ * PP_ + 255) / 256), dim3(256), 0, stream>>>(target, pack, cov);
    k_ce2<<<dim3(NB_CE), dim3(256), 0, stream>>>(score, target, hm, cov);
    k_pool2<<<dim3(NB_PL), dim3(256), 0, stream>>>(hm, pack, pr, la);
    k_cov<<<dim3(NC_, 4, 3), dim3(192), 0, stream>>>(la, pr, cov);
    k_final<<<dim3(1), dim3(128), 0, stream>>>(cov, (float*)d_out);
}